// Round 1
// baseline (1356.913 us; speedup 1.0000x reference)
//
#include <hip/hip_runtime.h>

#define HIDDEN 512
#define H4 128  // HIDDEN/4

// ---------------- CSR build ----------------

__global__ void count_kernel(const int* __restrict__ dst, int* __restrict__ cnt, int E) {
    int e = blockIdx.x * 256 + threadIdx.x;
    if (e < E) atomicAdd(&cnt[dst[e]], 1);
}

__global__ void norm_kernel(const int* __restrict__ cnt, float* __restrict__ norm, int N) {
    int i = blockIdx.x * 256 + threadIdx.x;
    if (i < N) norm[i] = rsqrtf((float)(cnt[i] + 1));  // +1 self-loop
}

__global__ void coef_kernel(const int* __restrict__ src, const int* __restrict__ dst,
                            const float* __restrict__ norm, float* __restrict__ coef, int E) {
    int e = blockIdx.x * 256 + threadIdx.x;
    if (e < E) coef[e] = norm[src[e]] * norm[dst[e]];
}

__global__ void exclusive_scan_kernel(const int* __restrict__ cnt, int* __restrict__ rowptr, int n) {
    __shared__ int buf[1024];
    __shared__ int carry_s;
    int tid = threadIdx.x;
    if (tid == 0) carry_s = 0;
    __syncthreads();
    for (int base = 0; base < n; base += 1024) {
        int i = base + tid;
        int v = (i < n) ? cnt[i] : 0;
        buf[tid] = v;
        __syncthreads();
        for (int off = 1; off < 1024; off <<= 1) {
            int t = (tid >= off) ? buf[tid - off] : 0;
            __syncthreads();
            buf[tid] += t;
            __syncthreads();
        }
        int incl = buf[tid];
        int carry = carry_s;
        if (i < n) rowptr[i] = carry + incl - v;  // exclusive
        __syncthreads();
        if (tid == 1023) carry_s = carry + incl;
        __syncthreads();
    }
    if (tid == 0) rowptr[n] = carry_s;
}

__global__ void fill_kernel(const int* __restrict__ src, const int* __restrict__ dst,
                            const float* __restrict__ coef, int* __restrict__ cursor,
                            int* __restrict__ srcs, float* __restrict__ coefs, int E) {
    int e = blockIdx.x * 256 + threadIdx.x;
    if (e < E) {
        int p = atomicAdd(&cursor[dst[e]], 1);
        srcs[p]  = src[e];
        coefs[p] = coef[e];
    }
}

// ---------------- GEMM: C[M,N] = A[M,K] @ W[N,K]^T (+bias) ----------------
// Both operands K-contiguous (NT). 128x128 tile, BK=16, 256 threads, 8x8/thread.

template<bool HAS_BIAS>
__global__ __launch_bounds__(256)
void gemm_nt(const float* __restrict__ A, const float* __restrict__ W,
             const float* __restrict__ bias, float* __restrict__ C,
             int M, int N, int K) {
    constexpr int BM = 128, BN = 128, BK = 16, PAD = 4;
    __shared__ float As[BK][BM + PAD];
    __shared__ float Bs[BK][BN + PAD];

    const int tid = threadIdx.x;
    const int bm = blockIdx.x * BM;
    const int bn = blockIdx.y * BN;
    const int tx = tid & 15;
    const int ty = tid >> 4;
    const int lm = tid >> 2;         // 0..63 : row within half-tile
    const int lf = (tid & 3) * 4;    // k offset 0,4,8,12

    float acc[8][8];
    #pragma unroll
    for (int i = 0; i < 8; ++i)
        #pragma unroll
        for (int j = 0; j < 8; ++j) acc[i][j] = 0.f;

    for (int k0 = 0; k0 < K; k0 += BK) {
        #pragma unroll
        for (int h = 0; h < 2; ++h) {
            int m = lm + h * 64;
            int row = bm + m;
            float4 va = make_float4(0.f, 0.f, 0.f, 0.f);
            if (row < M) va = *(const float4*)(A + (size_t)row * K + k0 + lf);
            As[lf + 0][m] = va.x; As[lf + 1][m] = va.y;
            As[lf + 2][m] = va.z; As[lf + 3][m] = va.w;
            int col = bn + m;
            float4 vb = make_float4(0.f, 0.f, 0.f, 0.f);
            if (col < N) vb = *(const float4*)(W + (size_t)col * K + k0 + lf);
            Bs[lf + 0][m] = vb.x; Bs[lf + 1][m] = vb.y;
            Bs[lf + 2][m] = vb.z; Bs[lf + 3][m] = vb.w;
        }
        __syncthreads();
        #pragma unroll
        for (int kk = 0; kk < BK; ++kk) {
            float4 a0 = *(const float4*)&As[kk][ty * 4];
            float4 a1 = *(const float4*)&As[kk][64 + ty * 4];
            float4 b0 = *(const float4*)&Bs[kk][tx * 4];
            float4 b1 = *(const float4*)&Bs[kk][64 + tx * 4];
            float a[8] = {a0.x, a0.y, a0.z, a0.w, a1.x, a1.y, a1.z, a1.w};
            float b[8] = {b0.x, b0.y, b0.z, b0.w, b1.x, b1.y, b1.z, b1.w};
            #pragma unroll
            for (int i = 0; i < 8; ++i)
                #pragma unroll
                for (int j = 0; j < 8; ++j)
                    acc[i][j] = fmaf(a[i], b[j], acc[i][j]);
        }
        __syncthreads();
    }

    const bool fullN = (bn + BN <= N);
    #pragma unroll
    for (int i = 0; i < 8; ++i) {
        int row = bm + ((i < 4) ? (ty * 4 + i) : (64 + ty * 4 + i - 4));
        if (row >= M) continue;
        float* crow = C + (size_t)row * N;
        #pragma unroll
        for (int jh = 0; jh < 2; ++jh) {
            int col = bn + jh * 64 + tx * 4;
            float v[4] = {acc[i][jh * 4 + 0], acc[i][jh * 4 + 1],
                          acc[i][jh * 4 + 2], acc[i][jh * 4 + 3]};
            if (fullN) {
                if (HAS_BIAS) {
                    v[0] += bias[col + 0]; v[1] += bias[col + 1];
                    v[2] += bias[col + 2]; v[3] += bias[col + 3];
                }
                float4 o = make_float4(v[0], v[1], v[2], v[3]);
                *(float4*)(crow + col) = o;
            } else {
                #pragma unroll
                for (int jj = 0; jj < 4; ++jj) {
                    int c = col + jj;
                    if (c < N) crow[c] = HAS_BIAS ? (v[jj] + bias[c]) : v[jj];
                }
            }
        }
    }
}

// ---------------- Aggregation (gather form, fused self-loop+bias+relu) ----------------
// out[i] = relu( sum_{e: dst=i} coef[e]*h[src[e]] + norm[i]^2 * h[i] + b )

__global__ __launch_bounds__(128)
void aggregate_kernel(const float* __restrict__ h, const int* __restrict__ rowptr,
                      const int* __restrict__ srcs, const float* __restrict__ coefs,
                      const float* __restrict__ norm, const float* __restrict__ bias,
                      float* __restrict__ out, int N) {
    int node = blockIdx.x;
    int c = threadIdx.x;  // float4 column 0..127
    const float4* h4 = (const float4*)h;
    float4 self = h4[(size_t)node * H4 + c];
    float nv = norm[node];
    float invd = nv * nv;  // self-loop coef
    float4 acc;
    acc.x = self.x * invd; acc.y = self.y * invd;
    acc.z = self.z * invd; acc.w = self.w * invd;
    int beg = rowptr[node], end = rowptr[node + 1];
    for (int j = beg; j < end; ++j) {
        int s = srcs[j];
        float cf = coefs[j];
        float4 v = h4[(size_t)s * H4 + c];
        acc.x = fmaf(cf, v.x, acc.x);
        acc.y = fmaf(cf, v.y, acc.y);
        acc.z = fmaf(cf, v.z, acc.z);
        acc.w = fmaf(cf, v.w, acc.w);
    }
    float4 bv = ((const float4*)bias)[c];
    acc.x = fmaxf(acc.x + bv.x, 0.f);
    acc.y = fmaxf(acc.y + bv.y, 0.f);
    acc.z = fmaxf(acc.z + bv.z, 0.f);
    acc.w = fmaxf(acc.w + bv.w, 0.f);
    ((float4*)out)[(size_t)node * H4 + c] = acc;
}

// ---------------- launch ----------------

extern "C" void kernel_launch(void* const* d_in, const int* in_sizes, int n_in,
                              void* d_out, int out_size, void* d_ws, size_t ws_size,
                              hipStream_t stream) {
    const float* x  = (const float*)d_in[0];
    const int*   ei = (const int*)d_in[1];
    const float* W1 = (const float*)d_in[2];
    const float* b1 = (const float*)d_in[3];
    const float* W2 = (const float*)d_in[4];
    const float* b2 = (const float*)d_in[5];
    const float* Wc = (const float*)d_in[6];
    const float* bc = (const float*)d_in[7];

    const int N  = in_sizes[0] / HIDDEN;
    const int E  = in_sizes[1] / 2;
    const int NC = in_sizes[6] / HIDDEN;

    const int* src = ei;
    const int* dst = ei + E;

    char* ws = (char*)d_ws;
    int*   cnt    = (int*)(ws);                        // N ints
    int*   rowptr = (int*)(ws + (256 << 10));          // N+1 ints
    int*   cursor = (int*)(ws + (512 << 10));          // N ints
    float* normv  = (float*)(ws + (768 << 10));        // N floats
    float* coef   = (float*)(ws + (1 << 20));          // E floats (2MB)
    int*   srcs   = (int*)(ws + (3ull << 20));         // E ints
    float* coefs  = (float*)(ws + (5ull << 20));       // E floats
    float* h      = (float*)(ws + (8ull << 20));       // N*512 floats
    float* agg    = h + (size_t)N * HIDDEN;            // N*512 floats

    // CSR + normalization (recomputed every call; ws is re-poisoned)
    hipMemsetAsync(cnt, 0, N * sizeof(int), stream);
    count_kernel<<<(E + 255) / 256, 256, 0, stream>>>(dst, cnt, E);
    norm_kernel<<<(N + 255) / 256, 256, 0, stream>>>(cnt, normv, N);
    coef_kernel<<<(E + 255) / 256, 256, 0, stream>>>(src, dst, normv, coef, E);
    exclusive_scan_kernel<<<1, 1024, 0, stream>>>(cnt, rowptr, N);
    hipMemcpyAsync(cursor, rowptr, N * sizeof(int), hipMemcpyDeviceToDevice, stream);
    fill_kernel<<<(E + 255) / 256, 256, 0, stream>>>(src, dst, coef, cursor, srcs, coefs, E);

    dim3 gt((N + 127) / 128, (HIDDEN + 127) / 128);
    // layer 1
    gemm_nt<false><<<gt, 256, 0, stream>>>(x, W1, nullptr, h, N, HIDDEN, HIDDEN);
    aggregate_kernel<<<N, 128, 0, stream>>>(h, rowptr, srcs, coefs, normv, b1, agg, N);
    // layer 2
    gemm_nt<false><<<gt, 256, 0, stream>>>(agg, W2, nullptr, h, N, HIDDEN, HIDDEN);
    aggregate_kernel<<<N, 128, 0, stream>>>(h, rowptr, srcs, coefs, normv, b2, agg, N);
    // classifier head
    dim3 gc((N + 127) / 128, (NC + 127) / 128);
    gemm_nt<true><<<gc, 256, 0, stream>>>(agg, Wc, bc, (float*)d_out, N, NC, HIDDEN);
}

// Round 2
// 682.663 us; speedup vs baseline: 1.9877x; 1.9877x over previous
//
#include <hip/hip_runtime.h>

#define HIDDEN 512
#define NCHUNK 64            // HIDDEN/8 k-chunks per row
#define BLK_ELEMS (64 * 128 * 8)   // elements per (128-row x 512-col) tiled block

typedef __attribute__((ext_vector_type(8))) short short8;
typedef __attribute__((ext_vector_type(4))) float f32x4;

__device__ __forceinline__ unsigned short f2bf(float f) {
    unsigned u = __float_as_uint(f);
    unsigned r = (u + 0x7FFFu + ((u >> 16) & 1u)) >> 16;
    return (unsigned short)r;
}
__device__ __forceinline__ float bf2f(unsigned short h) {
    return __uint_as_float(((unsigned)h) << 16);
}

__device__ __forceinline__ void load_lds16(const unsigned short* g, unsigned short* l) {
    __builtin_amdgcn_global_load_lds(
        (const __attribute__((address_space(1))) unsigned int*)(g),
        (__attribute__((address_space(3))) unsigned int*)(l), 16, 0, 0);
}

// ---------------- CSR build ----------------

__global__ void count_kernel(const int* __restrict__ dst, int* __restrict__ cnt, int E) {
    int e = blockIdx.x * 256 + threadIdx.x;
    if (e < E) atomicAdd(&cnt[dst[e]], 1);
}

__global__ void norm_kernel(const int* __restrict__ cnt, float* __restrict__ norm, int N) {
    int i = blockIdx.x * 256 + threadIdx.x;
    if (i < N) norm[i] = rsqrtf((float)(cnt[i] + 1));
}

__global__ void coef_kernel(const int* __restrict__ src, const int* __restrict__ dst,
                            const float* __restrict__ norm, float* __restrict__ coef, int E) {
    int e = blockIdx.x * 256 + threadIdx.x;
    if (e < E) coef[e] = norm[src[e]] * norm[dst[e]];
}

__global__ void exclusive_scan_kernel(const int* __restrict__ cnt, int* __restrict__ rowptr, int n) {
    __shared__ int buf[1024];
    __shared__ int carry_s;
    int tid = threadIdx.x;
    if (tid == 0) carry_s = 0;
    __syncthreads();
    for (int base = 0; base < n; base += 1024) {
        int i = base + tid;
        int v = (i < n) ? cnt[i] : 0;
        buf[tid] = v;
        __syncthreads();
        for (int off = 1; off < 1024; off <<= 1) {
            int t = (tid >= off) ? buf[tid - off] : 0;
            __syncthreads();
            buf[tid] += t;
            __syncthreads();
        }
        int incl = buf[tid];
        int carry = carry_s;
        if (i < n) rowptr[i] = carry + incl - v;
        __syncthreads();
        if (tid == 1023) carry_s = carry + incl;
        __syncthreads();
    }
    if (tid == 0) rowptr[n] = carry_s;
}

__global__ void fill_kernel(const int* __restrict__ src, const int* __restrict__ dst,
                            const float* __restrict__ coef, int* __restrict__ cursor,
                            int* __restrict__ srcs, float* __restrict__ coefs, int E) {
    int e = blockIdx.x * 256 + threadIdx.x;
    if (e < E) {
        int p = atomicAdd(&cursor[dst[e]], 1);
        srcs[p]  = src[e];
        coefs[p] = coef[e];
    }
}

// ---------------- cast fp32 row-major -> tiled bf16 ----------------
// tiled layout: [row/128][kchunk(64)][row%128][8 bf16]

__global__ __launch_bounds__(256)
void cast_tiled_kernel(const float* __restrict__ src, unsigned short* __restrict__ dst,
                       int rows, int total_chunks) {
    int o = blockIdx.x * 256 + threadIdx.x;
    if (o >= total_chunks) return;
    int blk = o >> 13;          // /8192 chunks per block
    int rem = o & 8191;
    int g = rem >> 7;
    int m = rem & 127;
    int row = blk * 128 + m;
    short8 v;
    if (row < rows) {
        const float* p = src + (size_t)row * HIDDEN + g * 8;
        float4 f0 = *(const float4*)p;
        float4 f1 = *(const float4*)(p + 4);
        v[0] = (short)f2bf(f0.x); v[1] = (short)f2bf(f0.y);
        v[2] = (short)f2bf(f0.z); v[3] = (short)f2bf(f0.w);
        v[4] = (short)f2bf(f1.x); v[5] = (short)f2bf(f1.y);
        v[6] = (short)f2bf(f1.z); v[7] = (short)f2bf(f1.w);
    } else {
        v = (short8)0;
    }
    *(short8*)(dst + (size_t)o * 8) = v;
}

// ---------------- bf16 MFMA GEMM ----------------
// C[M,N] = A[M,K] @ W[N,K]^T, A/W in tiled bf16 layout, K=512.
// MODE 0: C bf16 row-major [M][512].  MODE 1: C fp32 [M][NC] + bias, col<NC guard.

template<int MODE>
__global__ __launch_bounds__(256)
void gemm_bf16(const unsigned short* __restrict__ At, const unsigned short* __restrict__ Bt,
               const float* __restrict__ bias, void* __restrict__ Cout,
               int M, int NC) {
    __shared__ __align__(16) unsigned short As[8 * 128 * 8];  // 16 KB: [g][m][8]
    __shared__ __align__(16) unsigned short Bs[8 * 128 * 8];

    const int tid = threadIdx.x;
    const int mb = blockIdx.x;
    const int nb = blockIdx.y;
    const int wid = tid >> 6;
    const int lane = tid & 63;
    const int wm = wid & 1, wn = wid >> 1;  // 2x2 waves, each 64x64
    const int lm = lane & 15;
    const int lq = lane >> 4;

    const unsigned short* Ab = At + (size_t)mb * BLK_ELEMS;
    const unsigned short* Bb = Bt + (size_t)nb * BLK_ELEMS;

    f32x4 acc[4][4];
    #pragma unroll
    for (int i = 0; i < 4; ++i)
        #pragma unroll
        for (int j = 0; j < 4; ++j) acc[i][j] = (f32x4)0.f;

    for (int kt = 0; kt < 8; ++kt) {
        __syncthreads();
        const unsigned short* ga = Ab + kt * (8 * 1024);
        const unsigned short* gb = Bb + kt * (8 * 1024);
        #pragma unroll
        for (int i = 0; i < 4; ++i) {
            int off = (tid + i * 256) * 8;   // 16B chunk per thread
            load_lds16(ga + off, As + off);
            load_lds16(gb + off, Bs + off);
        }
        __syncthreads();
        #pragma unroll
        for (int ks = 0; ks < 2; ++ks) {
            int g = ks * 4 + lq;
            int base = g * 1024 + lm * 8;
            short8 af[4], bfr[4];
            #pragma unroll
            for (int mt = 0; mt < 4; ++mt)
                af[mt] = *(const short8*)&As[base + (wm * 64 + mt * 16) * 8];
            #pragma unroll
            for (int nt = 0; nt < 4; ++nt)
                bfr[nt] = *(const short8*)&Bs[base + (wn * 64 + nt * 16) * 8];
            #pragma unroll
            for (int mt = 0; mt < 4; ++mt)
                #pragma unroll
                for (int nt = 0; nt < 4; ++nt)
                    acc[mt][nt] = __builtin_amdgcn_mfma_f32_16x16x32_bf16(
                        af[mt], bfr[nt], acc[mt][nt], 0, 0, 0);
        }
    }

    // epilogue: C/D layout col=lane&15, row=(lane>>4)*4+reg
    #pragma unroll
    for (int mt = 0; mt < 4; ++mt) {
        #pragma unroll
        for (int nt = 0; nt < 4; ++nt) {
            int col = nb * 128 + wn * 64 + nt * 16 + lm;
            f32x4 v = acc[mt][nt];
            #pragma unroll
            for (int r = 0; r < 4; ++r) {
                int row = mb * 128 + wm * 64 + mt * 16 + lq * 4 + r;
                if (row < M) {
                    if (MODE == 0) {
                        ((unsigned short*)Cout)[(size_t)row * HIDDEN + col] = f2bf(v[r]);
                    } else {
                        if (col < NC)
                            ((float*)Cout)[(size_t)row * NC + col] = v[r] + bias[col];
                    }
                }
            }
        }
    }
}

// ---------------- aggregation: gather + self-loop + bias + relu, tiled-bf16 out ----------------

__global__ __launch_bounds__(128)
void aggregate_kernel(const unsigned short* __restrict__ h, const int* __restrict__ rowptr,
                      const int* __restrict__ srcs, const float* __restrict__ coefs,
                      const float* __restrict__ norm, const float* __restrict__ bias,
                      unsigned short* __restrict__ out_t, int N) {
    int node = blockIdx.x;
    int c = threadIdx.x;  // owns cols 4c..4c+3
    const unsigned short* hrow = h + (size_t)node * HIDDEN + c * 4;
    uint2 sv = *(const uint2*)hrow;
    float nv = norm[node];
    float invd = nv * nv;
    float a0 = bf2f((unsigned short)(sv.x & 0xFFFF)) * invd;
    float a1 = bf2f((unsigned short)(sv.x >> 16)) * invd;
    float a2 = bf2f((unsigned short)(sv.y & 0xFFFF)) * invd;
    float a3 = bf2f((unsigned short)(sv.y >> 16)) * invd;
    int beg = rowptr[node], end = rowptr[node + 1];
    for (int j = beg; j < end; ++j) {
        int s = srcs[j];
        float cf = coefs[j];
        uint2 v = *(const uint2*)(h + (size_t)s * HIDDEN + c * 4);
        a0 = fmaf(cf, bf2f((unsigned short)(v.x & 0xFFFF)), a0);
        a1 = fmaf(cf, bf2f((unsigned short)(v.x >> 16)), a1);
        a2 = fmaf(cf, bf2f((unsigned short)(v.y & 0xFFFF)), a2);
        a3 = fmaf(cf, bf2f((unsigned short)(v.y >> 16)), a3);
    }
    const float* bp = bias + c * 4;
    a0 = fmaxf(a0 + bp[0], 0.f);
    a1 = fmaxf(a1 + bp[1], 0.f);
    a2 = fmaxf(a2 + bp[2], 0.f);
    a3 = fmaxf(a3 + bp[3], 0.f);
    // tiled write: [node/128][g=c>>1][node%128][8], our half-chunk is (c&1)*4
    size_t off = (size_t)(node >> 7) * BLK_ELEMS + (c >> 1) * 1024 + (node & 127) * 8 + (c & 1) * 4;
    uint2 o;
    o.x = (unsigned)f2bf(a0) | ((unsigned)f2bf(a1) << 16);
    o.y = (unsigned)f2bf(a2) | ((unsigned)f2bf(a3) << 16);
    *(uint2*)(out_t + off) = o;
}

// ---------------- launch ----------------

extern "C" void kernel_launch(void* const* d_in, const int* in_sizes, int n_in,
                              void* d_out, int out_size, void* d_ws, size_t ws_size,
                              hipStream_t stream) {
    const float* x  = (const float*)d_in[0];
    const int*   ei = (const int*)d_in[1];
    const float* W1 = (const float*)d_in[2];
    const float* b1 = (const float*)d_in[3];
    const float* W2 = (const float*)d_in[4];
    const float* b2 = (const float*)d_in[5];
    const float* Wc = (const float*)d_in[6];
    const float* bc = (const float*)d_in[7];

    const int N  = in_sizes[0] / HIDDEN;      // 50000
    const int E  = in_sizes[1] / 2;           // 500000
    const int NC = in_sizes[6] / HIDDEN;      // 100
    const int NB = (N + 127) / 128;           // 391 row blocks
    const int Mp = NB * 128;

    const int* src = ei;
    const int* dst = ei + E;

    char* ws = (char*)d_ws;
    int*   cnt    = (int*)(ws);
    int*   rowptr = (int*)(ws + (256 << 10));
    int*   cursor = (int*)(ws + (512 << 10));
    float* normv  = (float*)(ws + (768 << 10));
    float* coef   = (float*)(ws + (1 << 20));
    int*   srcs   = (int*)(ws + (3ull << 20));
    float* coefs  = (float*)(ws + (5ull << 20));
    unsigned short* W1t = (unsigned short*)(ws + (7ull << 20));            // 512 KB
    unsigned short* W2t = (unsigned short*)(ws + (7ull << 20) + (512 << 10));
    unsigned short* Wct = (unsigned short*)(ws + (8ull << 20));            // 128 KB
    unsigned short* bufA = (unsigned short*)(ws + (16ull << 20));          // Mp*512 bf16
    unsigned short* bufB = (unsigned short*)(ws + (80ull << 20));
    unsigned short* hbuf = (unsigned short*)(ws + (144ull << 20));         // M*512 bf16 row-major

    // CSR + normalization
    hipMemsetAsync(cnt, 0, N * sizeof(int), stream);
    count_kernel<<<(E + 255) / 256, 256, 0, stream>>>(dst, cnt, E);
    norm_kernel<<<(N + 255) / 256, 256, 0, stream>>>(cnt, normv, N);
    coef_kernel<<<(E + 255) / 256, 256, 0, stream>>>(src, dst, normv, coef, E);
    exclusive_scan_kernel<<<1, 1024, 0, stream>>>(cnt, rowptr, N);
    hipMemcpyAsync(cursor, rowptr, N * sizeof(int), hipMemcpyDeviceToDevice, stream);
    fill_kernel<<<(E + 255) / 256, 256, 0, stream>>>(src, dst, coef, cursor, srcs, coefs, E);

    // casts to tiled bf16
    int xchunks = NB * 8192;
    cast_tiled_kernel<<<(xchunks + 255) / 256, 256, 0, stream>>>(x, bufA, N, xchunks);
    cast_tiled_kernel<<<128, 256, 0, stream>>>(W1, W1t, HIDDEN, 4 * 8192);
    cast_tiled_kernel<<<128, 256, 0, stream>>>(W2, W2t, HIDDEN, 4 * 8192);
    cast_tiled_kernel<<<32, 256, 0, stream>>>(Wc, Wct, NC, 8192);

    dim3 gh(NB, 4);
    // layer 1
    gemm_bf16<0><<<gh, 256, 0, stream>>>(bufA, W1t, nullptr, hbuf, N, HIDDEN);
    aggregate_kernel<<<N, 128, 0, stream>>>(hbuf, rowptr, srcs, coefs, normv, b1, bufB, N);
    // layer 2
    gemm_bf16<0><<<gh, 256, 0, stream>>>(bufB, W2t, nullptr, hbuf, N, HIDDEN);
    aggregate_kernel<<<N, 128, 0, stream>>>(hbuf, rowptr, srcs, coefs, normv, b2, bufA, N);
    // head
    dim3 gc(NB, 1);
    gemm_bf16<1><<<gc, 256, 0, stream>>>(bufA, Wct, bc, d_out, N, NC);
}

// Round 3
// 668.644 us; speedup vs baseline: 2.0293x; 1.0210x over previous
//
#include <hip/hip_runtime.h>

#define HIDDEN 512
#define BLK_ELEMS (64 * 128 * 8)   // elements per (128-row x 512-col) tiled block

typedef __attribute__((ext_vector_type(8))) short short8;
typedef __attribute__((ext_vector_type(4))) float f32x4;

__device__ __forceinline__ unsigned short f2bf(float f) {
    unsigned u = __float_as_uint(f);
    unsigned r = (u + 0x7FFFu + ((u >> 16) & 1u)) >> 16;
    return (unsigned short)r;
}
__device__ __forceinline__ float bf2f(unsigned short h) {
    return __uint_as_float(((unsigned)h) << 16);
}

__device__ __forceinline__ void load_lds16(const unsigned short* g, unsigned short* l) {
    __builtin_amdgcn_global_load_lds(
        (const __attribute__((address_space(1))) unsigned int*)(g),
        (__attribute__((address_space(3))) unsigned int*)(l), 16, 0, 0);
}

__device__ __forceinline__ void acc8(uint4 v, float cf, float* a) {
    a[0] = fmaf(cf, bf2f((unsigned short)(v.x & 0xFFFF)), a[0]);
    a[1] = fmaf(cf, bf2f((unsigned short)(v.x >> 16)),    a[1]);
    a[2] = fmaf(cf, bf2f((unsigned short)(v.y & 0xFFFF)), a[2]);
    a[3] = fmaf(cf, bf2f((unsigned short)(v.y >> 16)),    a[3]);
    a[4] = fmaf(cf, bf2f((unsigned short)(v.z & 0xFFFF)), a[4]);
    a[5] = fmaf(cf, bf2f((unsigned short)(v.z >> 16)),    a[5]);
    a[6] = fmaf(cf, bf2f((unsigned short)(v.w & 0xFFFF)), a[6]);
    a[7] = fmaf(cf, bf2f((unsigned short)(v.w >> 16)),    a[7]);
}

// ---------------- CSR build ----------------

__global__ void count_kernel(const int* __restrict__ dst, int* __restrict__ cnt, int E) {
    int e = blockIdx.x * 256 + threadIdx.x;
    if (e < E) atomicAdd(&cnt[dst[e]], 1);
}

__global__ void norm_kernel(const int* __restrict__ cnt, float* __restrict__ norm, int N) {
    int i = blockIdx.x * 256 + threadIdx.x;
    if (i < N) norm[i] = rsqrtf((float)(cnt[i] + 1));
}

// two-phase scan: thread t owns elements [t*per, (t+1)*per); writes rowptr AND cursor
__global__ __launch_bounds__(1024)
void scan_kernel(const int* __restrict__ cnt, int* __restrict__ rowptr,
                 int* __restrict__ cursor, int n) {
    __shared__ int sums[1024];
    int tid = threadIdx.x;
    int per = (n + 1023) >> 10;
    int start = tid * per;
    int s = 0;
    for (int k = 0; k < per; ++k) {
        int i = start + k;
        if (i < n) s += cnt[i];
    }
    sums[tid] = s;
    __syncthreads();
    for (int off = 1; off < 1024; off <<= 1) {
        int t = (tid >= off) ? sums[tid - off] : 0;
        __syncthreads();
        sums[tid] += t;
        __syncthreads();
    }
    int run = sums[tid] - s;  // exclusive prefix of this thread's run
    for (int k = 0; k < per; ++k) {
        int i = start + k;
        if (i < n) {
            rowptr[i] = run;
            cursor[i] = run;
            run += cnt[i];
        }
    }
    if (tid == 1023) rowptr[n] = run;
}

// fill CSR adjacency with fused coef computation; epair = (src, coef-bits)
__global__ void fill_kernel(const int* __restrict__ src, const int* __restrict__ dst,
                            const float* __restrict__ norm, int* __restrict__ cursor,
                            int2* __restrict__ epair, int E) {
    int e = blockIdx.x * 256 + threadIdx.x;
    if (e < E) {
        int s = src[e], d = dst[e];
        float cf = norm[s] * norm[d];
        int p = atomicAdd(&cursor[d], 1);
        epair[p] = make_int2(s, __float_as_int(cf));
    }
}

// ---------------- cast fp32 row-major -> tiled bf16 ----------------
// tiled layout: [row/128][kchunk(64)][row%128][8 bf16]

__global__ __launch_bounds__(256)
void cast_tiled_kernel(const float* __restrict__ src, unsigned short* __restrict__ dst,
                       int rows, int total_chunks) {
    int o = blockIdx.x * 256 + threadIdx.x;
    if (o >= total_chunks) return;
    int blk = o >> 13;
    int rem = o & 8191;
    int g = rem >> 7;
    int m = rem & 127;
    int row = blk * 128 + m;
    short8 v;
    if (row < rows) {
        const float* p = src + (size_t)row * HIDDEN + g * 8;
        float4 f0 = *(const float4*)p;
        float4 f1 = *(const float4*)(p + 4);
        v[0] = (short)f2bf(f0.x); v[1] = (short)f2bf(f0.y);
        v[2] = (short)f2bf(f0.z); v[3] = (short)f2bf(f0.w);
        v[4] = (short)f2bf(f1.x); v[5] = (short)f2bf(f1.y);
        v[6] = (short)f2bf(f1.z); v[7] = (short)f2bf(f1.w);
    } else {
        v = (short8)0;
    }
    *(short8*)(dst + (size_t)o * 8) = v;
}

// ---------------- bf16 MFMA GEMM ----------------
// C[M,N] = A[M,K] @ W[N,K]^T, A/W in tiled bf16 layout, K=512.
// MODE 0: C bf16 row-major [M][512].  MODE 1: C fp32 [M][NC] + bias, col<NC guard.

template<int MODE>
__global__ __launch_bounds__(256)
void gemm_bf16(const unsigned short* __restrict__ At, const unsigned short* __restrict__ Bt,
               const float* __restrict__ bias, void* __restrict__ Cout,
               int M, int NC) {
    __shared__ __align__(16) unsigned short As[8 * 128 * 8];  // 16 KB: [g][m][8]
    __shared__ __align__(16) unsigned short Bs[8 * 128 * 8];

    const int tid = threadIdx.x;
    const int mb = blockIdx.x;
    const int nb = blockIdx.y;
    const int wid = tid >> 6;
    const int lane = tid & 63;
    const int wm = wid & 1, wn = wid >> 1;
    const int lm = lane & 15;
    const int lq = lane >> 4;

    const unsigned short* Ab = At + (size_t)mb * BLK_ELEMS;
    const unsigned short* Bb = Bt + (size_t)nb * BLK_ELEMS;

    f32x4 acc[4][4];
    #pragma unroll
    for (int i = 0; i < 4; ++i)
        #pragma unroll
        for (int j = 0; j < 4; ++j) acc[i][j] = (f32x4)0.f;

    for (int kt = 0; kt < 8; ++kt) {
        __syncthreads();
        const unsigned short* ga = Ab + kt * (8 * 1024);
        const unsigned short* gb = Bb + kt * (8 * 1024);
        #pragma unroll
        for (int i = 0; i < 4; ++i) {
            int off = (tid + i * 256) * 8;
            load_lds16(ga + off, As + off);
            load_lds16(gb + off, Bs + off);
        }
        __syncthreads();
        #pragma unroll
        for (int ks = 0; ks < 2; ++ks) {
            int g = ks * 4 + lq;
            int base = g * 1024 + lm * 8;
            short8 af[4], bfr[4];
            #pragma unroll
            for (int mt = 0; mt < 4; ++mt)
                af[mt] = *(const short8*)&As[base + (wm * 64 + mt * 16) * 8];
            #pragma unroll
            for (int nt = 0; nt < 4; ++nt)
                bfr[nt] = *(const short8*)&Bs[base + (wn * 64 + nt * 16) * 8];
            #pragma unroll
            for (int mt = 0; mt < 4; ++mt)
                #pragma unroll
                for (int nt = 0; nt < 4; ++nt)
                    acc[mt][nt] = __builtin_amdgcn_mfma_f32_16x16x32_bf16(
                        af[mt], bfr[nt], acc[mt][nt], 0, 0, 0);
        }
    }

    #pragma unroll
    for (int mt = 0; mt < 4; ++mt) {
        #pragma unroll
        for (int nt = 0; nt < 4; ++nt) {
            int col = nb * 128 + wn * 64 + nt * 16 + lm;
            f32x4 v = acc[mt][nt];
            #pragma unroll
            for (int r = 0; r < 4; ++r) {
                int row = mb * 128 + wm * 64 + mt * 16 + lq * 4 + r;
                if (row < M) {
                    if (MODE == 0) {
                        ((unsigned short*)Cout)[(size_t)row * HIDDEN + col] = f2bf(v[r]);
                    } else {
                        if (col < NC)
                            ((float*)Cout)[(size_t)row * NC + col] = v[r] + bias[col];
                    }
                }
            }
        }
    }
}

// ---------------- aggregation: wave-per-node, 4-deep unrolled gather ----------------
// out[i] = relu( sum_e coef[e]*h[src[e]] + norm[i]^2*h[i] + b ), written tiled-bf16

__global__ __launch_bounds__(256)
void aggregate_kernel(const unsigned short* __restrict__ h, const int* __restrict__ rowptr,
                      const int2* __restrict__ epair, const float* __restrict__ norm,
                      const float* __restrict__ bias, unsigned short* __restrict__ out_t,
                      int N) {
    const int wave = threadIdx.x >> 6;
    const int lane = threadIdx.x & 63;
    const int node = blockIdx.x * 4 + wave;
    if (node >= N) return;
    const uint4* h4 = (const uint4*)h;   // 64 chunks of 16B per row
    const int c = lane;

    float a[8];
    {
        uint4 sv = h4[(size_t)node * 64 + c];
        float nv = norm[node];
        float invd = nv * nv;
        a[0] = a[1] = a[2] = a[3] = a[4] = a[5] = a[6] = a[7] = 0.f;
        acc8(sv, invd, a);
    }

    int beg = rowptr[node], end = rowptr[node + 1];
    int j = beg;
    for (; j + 4 <= end; j += 4) {
        int2 p0 = epair[j + 0];
        int2 p1 = epair[j + 1];
        int2 p2 = epair[j + 2];
        int2 p3 = epair[j + 3];
        uint4 v0 = h4[(size_t)p0.x * 64 + c];
        uint4 v1 = h4[(size_t)p1.x * 64 + c];
        uint4 v2 = h4[(size_t)p2.x * 64 + c];
        uint4 v3 = h4[(size_t)p3.x * 64 + c];
        acc8(v0, __int_as_float(p0.y), a);
        acc8(v1, __int_as_float(p1.y), a);
        acc8(v2, __int_as_float(p2.y), a);
        acc8(v3, __int_as_float(p3.y), a);
    }
    for (; j < end; ++j) {
        int2 p = epair[j];
        uint4 v = h4[(size_t)p.x * 64 + c];
        acc8(v, __int_as_float(p.y), a);
    }

    const float4 b0 = *(const float4*)(bias + c * 8);
    const float4 b1 = *(const float4*)(bias + c * 8 + 4);
    a[0] = fmaxf(a[0] + b0.x, 0.f); a[1] = fmaxf(a[1] + b0.y, 0.f);
    a[2] = fmaxf(a[2] + b0.z, 0.f); a[3] = fmaxf(a[3] + b0.w, 0.f);
    a[4] = fmaxf(a[4] + b1.x, 0.f); a[5] = fmaxf(a[5] + b1.y, 0.f);
    a[6] = fmaxf(a[6] + b1.z, 0.f); a[7] = fmaxf(a[7] + b1.w, 0.f);

    // tiled write: lane owns chunk g=c of this node's row
    size_t off = (size_t)(node >> 7) * BLK_ELEMS + (size_t)c * 1024 + (node & 127) * 8;
    uint4 o;
    o.x = (unsigned)f2bf(a[0]) | ((unsigned)f2bf(a[1]) << 16);
    o.y = (unsigned)f2bf(a[2]) | ((unsigned)f2bf(a[3]) << 16);
    o.z = (unsigned)f2bf(a[4]) | ((unsigned)f2bf(a[5]) << 16);
    o.w = (unsigned)f2bf(a[6]) | ((unsigned)f2bf(a[7]) << 16);
    *(uint4*)(out_t + off) = o;
}

// ---------------- launch ----------------

extern "C" void kernel_launch(void* const* d_in, const int* in_sizes, int n_in,
                              void* d_out, int out_size, void* d_ws, size_t ws_size,
                              hipStream_t stream) {
    const float* x  = (const float*)d_in[0];
    const int*   ei = (const int*)d_in[1];
    const float* W1 = (const float*)d_in[2];
    const float* b1 = (const float*)d_in[3];
    const float* W2 = (const float*)d_in[4];
    const float* b2 = (const float*)d_in[5];
    const float* Wc = (const float*)d_in[6];
    const float* bc = (const float*)d_in[7];

    const int N  = in_sizes[0] / HIDDEN;      // 50000
    const int E  = in_sizes[1] / 2;           // 500000
    const int NC = in_sizes[6] / HIDDEN;      // 100
    const int NB = (N + 127) / 128;           // 391

    const int* src = ei;
    const int* dst = ei + E;

    char* ws = (char*)d_ws;
    int*   cnt    = (int*)(ws);
    int*   rowptr = (int*)(ws + (256 << 10));
    int*   cursor = (int*)(ws + (512 << 10));
    float* normv  = (float*)(ws + (768 << 10));
    int2*  epair  = (int2*)(ws + (1ull << 20));                 // E*8 B = 4 MB
    unsigned short* W1t = (unsigned short*)(ws + (6ull << 20));
    unsigned short* W2t = (unsigned short*)(ws + (6ull << 20) + (512 << 10));
    unsigned short* Wct = (unsigned short*)(ws + (7ull << 20));
    unsigned short* bufA = (unsigned short*)(ws + (16ull << 20));
    unsigned short* bufB = (unsigned short*)(ws + (80ull << 20));
    unsigned short* hbuf = (unsigned short*)(ws + (144ull << 20));

    // CSR + normalization
    hipMemsetAsync(cnt, 0, N * sizeof(int), stream);
    count_kernel<<<(E + 255) / 256, 256, 0, stream>>>(dst, cnt, E);
    norm_kernel<<<(N + 255) / 256, 256, 0, stream>>>(cnt, normv, N);
    scan_kernel<<<1, 1024, 0, stream>>>(cnt, rowptr, cursor, N);
    fill_kernel<<<(E + 255) / 256, 256, 0, stream>>>(src, dst, normv, cursor, epair, E);

    // casts to tiled bf16
    int xchunks = NB * 8192;
    cast_tiled_kernel<<<(xchunks + 255) / 256, 256, 0, stream>>>(x, bufA, N, xchunks);
    cast_tiled_kernel<<<128, 256, 0, stream>>>(W1, W1t, HIDDEN, 4 * 8192);
    cast_tiled_kernel<<<128, 256, 0, stream>>>(W2, W2t, HIDDEN, 4 * 8192);
    cast_tiled_kernel<<<32, 256, 0, stream>>>(Wc, Wct, NC, 8192);

    dim3 gh(NB, 4);
    // layer 1
    gemm_bf16<0><<<gh, 256, 0, stream>>>(bufA, W1t, nullptr, hbuf, N, HIDDEN);
    aggregate_kernel<<<(N + 3) / 4, 256, 0, stream>>>(hbuf, rowptr, epair, normv, b1, bufB, N);
    // layer 2
    gemm_bf16<0><<<gh, 256, 0, stream>>>(bufB, W2t, nullptr, hbuf, N, HIDDEN);
    aggregate_kernel<<<(N + 3) / 4, 256, 0, stream>>>(hbuf, rowptr, epair, normv, b2, bufA, N);
    // head
    dim3 gc(NB, 1);
    gemm_bf16<1><<<gc, 256, 0, stream>>>(bufA, Wct, bc, d_out, N, NC);
}

// Round 5
// 560.003 us; speedup vs baseline: 2.4230x; 1.1940x over previous
//
#include <hip/hip_runtime.h>

#define HIDDEN 512
#define BLK_ELEMS (64 * 128 * 8)   // elements per (128-row x 512-col) tiled block

typedef __attribute__((ext_vector_type(8))) short short8;
typedef __attribute__((ext_vector_type(4))) float f32x4;

__device__ __forceinline__ unsigned short f2bf(float f) {
    unsigned u = __float_as_uint(f);
    unsigned r = (u + 0x7FFFu + ((u >> 16) & 1u)) >> 16;
    return (unsigned short)r;
}
__device__ __forceinline__ float bf2f(unsigned short h) {
    return __uint_as_float(((unsigned)h) << 16);
}

__device__ __forceinline__ void load_lds16(const unsigned short* g, unsigned short* l) {
    __builtin_amdgcn_global_load_lds(
        (const __attribute__((address_space(1))) unsigned int*)(g),
        (__attribute__((address_space(3))) unsigned int*)(l), 16, 0, 0);
}

__device__ __forceinline__ void acc8(uint4 v, float cf, float* a) {
    a[0] = fmaf(cf, bf2f((unsigned short)(v.x & 0xFFFF)), a[0]);
    a[1] = fmaf(cf, bf2f((unsigned short)(v.x >> 16)),    a[1]);
    a[2] = fmaf(cf, bf2f((unsigned short)(v.y & 0xFFFF)), a[2]);
    a[3] = fmaf(cf, bf2f((unsigned short)(v.y >> 16)),    a[3]);
    a[4] = fmaf(cf, bf2f((unsigned short)(v.z & 0xFFFF)), a[4]);
    a[5] = fmaf(cf, bf2f((unsigned short)(v.z >> 16)),    a[5]);
    a[6] = fmaf(cf, bf2f((unsigned short)(v.w & 0xFFFF)), a[6]);
    a[7] = fmaf(cf, bf2f((unsigned short)(v.w >> 16)),    a[7]);
}

// ---------------- CSR build ----------------

__global__ void count_kernel(const int* __restrict__ dst, int* __restrict__ cnt, int E) {
    int e = blockIdx.x * 256 + threadIdx.x;
    if (e < E) atomicAdd(&cnt[dst[e]], 1);
}

__global__ void norm_kernel(const int* __restrict__ cnt, float* __restrict__ norm, int N) {
    int i = blockIdx.x * 256 + threadIdx.x;
    if (i < N) norm[i] = rsqrtf((float)(cnt[i] + 1));
}

// ---- 3-phase multi-block exclusive scan of cnt -> rowptr (+cursor copy) ----

__global__ __launch_bounds__(256)
void bsum_kernel(const int* __restrict__ cnt, int* __restrict__ bsums, int n) {
    __shared__ int red[256];
    int tid = threadIdx.x;
    int i = blockIdx.x * 256 + tid;
    red[tid] = (i < n) ? cnt[i] : 0;
    __syncthreads();
    #pragma unroll
    for (int off = 128; off > 0; off >>= 1) {
        if (tid < off) red[tid] += red[tid + off];
        __syncthreads();
    }
    if (tid == 0) bsums[blockIdx.x] = red[0];
}

// scans nb (<=256) block sums; writes exclusive offsets + total into rowptr[n]
__global__ __launch_bounds__(256)
void bscan_kernel(const int* __restrict__ bsums, int* __restrict__ boffs,
                  int* __restrict__ rowptr_n, int nb) {
    __shared__ int buf[256];
    int tid = threadIdx.x;
    int v = (tid < nb) ? bsums[tid] : 0;
    buf[tid] = v;
    __syncthreads();
    #pragma unroll
    for (int off = 1; off < 256; off <<= 1) {
        int t = (tid >= off) ? buf[tid - off] : 0;
        __syncthreads();
        buf[tid] += t;
        __syncthreads();
    }
    if (tid < nb) boffs[tid] = buf[tid] - v;
    if (tid == 255) rowptr_n[0] = buf[255];
}

__global__ __launch_bounds__(256)
void scan_final_kernel(const int* __restrict__ cnt, const int* __restrict__ boffs,
                       int* __restrict__ rowptr, int* __restrict__ cursor, int n) {
    __shared__ int buf[256];
    int tid = threadIdx.x;
    int i = blockIdx.x * 256 + tid;
    int v = (i < n) ? cnt[i] : 0;
    buf[tid] = v;
    __syncthreads();
    #pragma unroll
    for (int off = 1; off < 256; off <<= 1) {
        int t = (tid >= off) ? buf[tid - off] : 0;
        __syncthreads();
        buf[tid] += t;
        __syncthreads();
    }
    if (i < n) {
        int ex = boffs[blockIdx.x] + buf[tid] - v;
        rowptr[i] = ex;
        cursor[i] = ex;
    }
}

// fill CSR adjacency with fused coef computation; epair = (src, coef-bits)
__global__ void fill_kernel(const int* __restrict__ src, const int* __restrict__ dst,
                            const float* __restrict__ norm, int* __restrict__ cursor,
                            int2* __restrict__ epair, int E) {
    int e = blockIdx.x * 256 + threadIdx.x;
    if (e < E) {
        int s = src[e], d = dst[e];
        float cf = norm[s] * norm[d];
        int p = atomicAdd(&cursor[d], 1);
        epair[p] = make_int2(s, __float_as_int(cf));
    }
}

// ---------------- cast fp32 row-major -> tiled bf16 ----------------
// tiled layout: [row/128][kchunk(64)][row%128][8 bf16]

__global__ __launch_bounds__(256)
void cast_tiled_kernel(const float* __restrict__ src, unsigned short* __restrict__ dst,
                       int rows, int total_chunks) {
    int o = blockIdx.x * 256 + threadIdx.x;
    if (o >= total_chunks) return;
    int blk = o >> 13;
    int rem = o & 8191;
    int g = rem >> 7;
    int m = rem & 127;
    int row = blk * 128 + m;
    short8 v;
    if (row < rows) {
        const float* p = src + (size_t)row * HIDDEN + g * 8;
        float4 f0 = *(const float4*)p;
        float4 f1 = *(const float4*)(p + 4);
        v[0] = (short)f2bf(f0.x); v[1] = (short)f2bf(f0.y);
        v[2] = (short)f2bf(f0.z); v[3] = (short)f2bf(f0.w);
        v[4] = (short)f2bf(f1.x); v[5] = (short)f2bf(f1.y);
        v[6] = (short)f2bf(f1.z); v[7] = (short)f2bf(f1.w);
    } else {
        v = (short8)0;
    }
    *(short8*)(dst + (size_t)o * 8) = v;
}

// ---------------- bf16 MFMA GEMM ----------------
// C[M,N] = A[M,K] @ W[N,K]^T, A/W in tiled bf16 layout, K=512.
// MODE 0: C bf16 row-major [M][512].  MODE 1: C fp32 [M][NC] + bias, col<NC guard.

template<int MODE>
__global__ __launch_bounds__(256)
void gemm_bf16(const unsigned short* __restrict__ At, const unsigned short* __restrict__ Bt,
               const float* __restrict__ bias, void* __restrict__ Cout,
               int M, int NC) {
    __shared__ __align__(16) unsigned short As[8 * 128 * 8];  // 16 KB: [g][m][8]
    __shared__ __align__(16) unsigned short Bs[8 * 128 * 8];

    const int tid = threadIdx.x;
    const int mb = blockIdx.x;
    const int nb = blockIdx.y;
    const int wid = tid >> 6;
    const int lane = tid & 63;
    const int wm = wid & 1, wn = wid >> 1;
    const int lm = lane & 15;
    const int lq = lane >> 4;

    const unsigned short* Ab = At + (size_t)mb * BLK_ELEMS;
    const unsigned short* Bb = Bt + (size_t)nb * BLK_ELEMS;

    f32x4 acc[4][4];
    #pragma unroll
    for (int i = 0; i < 4; ++i)
        #pragma unroll
        for (int j = 0; j < 4; ++j) acc[i][j] = (f32x4)0.f;

    for (int kt = 0; kt < 8; ++kt) {
        __syncthreads();
        const unsigned short* ga = Ab + kt * (8 * 1024);
        const unsigned short* gb = Bb + kt * (8 * 1024);
        #pragma unroll
        for (int i = 0; i < 4; ++i) {
            int off = (tid + i * 256) * 8;
            load_lds16(ga + off, As + off);
            load_lds16(gb + off, Bs + off);
        }
        __syncthreads();
        #pragma unroll
        for (int ks = 0; ks < 2; ++ks) {
            int g = ks * 4 + lq;
            int base = g * 1024 + lm * 8;
            short8 af[4], bfr[4];
            #pragma unroll
            for (int mt = 0; mt < 4; ++mt)
                af[mt] = *(const short8*)&As[base + (wm * 64 + mt * 16) * 8];
            #pragma unroll
            for (int nt = 0; nt < 4; ++nt)
                bfr[nt] = *(const short8*)&Bs[base + (wn * 64 + nt * 16) * 8];
            #pragma unroll
            for (int mt = 0; mt < 4; ++mt)
                #pragma unroll
                for (int nt = 0; nt < 4; ++nt)
                    acc[mt][nt] = __builtin_amdgcn_mfma_f32_16x16x32_bf16(
                        af[mt], bfr[nt], acc[mt][nt], 0, 0, 0);
        }
    }

    #pragma unroll
    for (int mt = 0; mt < 4; ++mt) {
        #pragma unroll
        for (int nt = 0; nt < 4; ++nt) {
            int col = nb * 128 + wn * 64 + nt * 16 + lm;
            f32x4 v = acc[mt][nt];
            #pragma unroll
            for (int r = 0; r < 4; ++r) {
                int row = mb * 128 + wm * 64 + mt * 16 + lq * 4 + r;
                if (row < M) {
                    if (MODE == 0) {
                        ((unsigned short*)Cout)[(size_t)row * HIDDEN + col] = f2bf(v[r]);
                    } else {
                        if (col < NC)
                            ((float*)Cout)[(size_t)row * NC + col] = v[r] + bias[col];
                    }
                }
            }
        }
    }
}

// ---------------- aggregation: wave-per-node, 4-deep unrolled gather ----------------
// out[i] = relu( sum_e coef[e]*h[src[e]] + norm[i]^2*h[i] + b ), written tiled-bf16

__global__ __launch_bounds__(256)
void aggregate_kernel(const unsigned short* __restrict__ h, const int* __restrict__ rowptr,
                      const int2* __restrict__ epair, const float* __restrict__ norm,
                      const float* __restrict__ bias, unsigned short* __restrict__ out_t,
                      int N) {
    const int wave = threadIdx.x >> 6;
    const int lane = threadIdx.x & 63;
    const int node = blockIdx.x * 4 + wave;
    if (node >= N) return;
    const uint4* h4 = (const uint4*)h;   // 64 chunks of 16B per row
    const int c = lane;

    float a[8];
    {
        uint4 sv = h4[(size_t)node * 64 + c];
        float nv = norm[node];
        float invd = nv * nv;
        a[0] = a[1] = a[2] = a[3] = a[4] = a[5] = a[6] = a[7] = 0.f;
        acc8(sv, invd, a);
    }

    int beg = rowptr[node], end = rowptr[node + 1];
    int j = beg;
    for (; j + 4 <= end; j += 4) {
        int2 p0 = epair[j + 0];
        int2 p1 = epair[j + 1];
        int2 p2 = epair[j + 2];
        int2 p3 = epair[j + 3];
        uint4 v0 = h4[(size_t)p0.x * 64 + c];
        uint4 v1 = h4[(size_t)p1.x * 64 + c];
        uint4 v2 = h4[(size_t)p2.x * 64 + c];
        uint4 v3 = h4[(size_t)p3.x * 64 + c];
        acc8(v0, __int_as_float(p0.y), a);
        acc8(v1, __int_as_float(p1.y), a);
        acc8(v2, __int_as_float(p2.y), a);
        acc8(v3, __int_as_float(p3.y), a);
    }
    for (; j < end; ++j) {
        int2 p = epair[j];
        uint4 v = h4[(size_t)p.x * 64 + c];
        acc8(v, __int_as_float(p.y), a);
    }

    const float4 b0 = *(const float4*)(bias + c * 8);
    const float4 b1 = *(const float4*)(bias + c * 8 + 4);
    a[0] = fmaxf(a[0] + b0.x, 0.f); a[1] = fmaxf(a[1] + b0.y, 0.f);
    a[2] = fmaxf(a[2] + b0.z, 0.f); a[3] = fmaxf(a[3] + b0.w, 0.f);
    a[4] = fmaxf(a[4] + b1.x, 0.f); a[5] = fmaxf(a[5] + b1.y, 0.f);
    a[6] = fmaxf(a[6] + b1.z, 0.f); a[7] = fmaxf(a[7] + b1.w, 0.f);

    // tiled write: lane owns chunk g=c of this node's row
    size_t off = (size_t)(node >> 7) * BLK_ELEMS + (size_t)c * 1024 + (node & 127) * 8;
    uint4 o;
    o.x = (unsigned)f2bf(a[0]) | ((unsigned)f2bf(a[1]) << 16);
    o.y = (unsigned)f2bf(a[2]) | ((unsigned)f2bf(a[3]) << 16);
    o.z = (unsigned)f2bf(a[4]) | ((unsigned)f2bf(a[5]) << 16);
    o.w = (unsigned)f2bf(a[6]) | ((unsigned)f2bf(a[7]) << 16);
    *(uint4*)(out_t + off) = o;
}

// ---------------- launch ----------------

extern "C" void kernel_launch(void* const* d_in, const int* in_sizes, int n_in,
                              void* d_out, int out_size, void* d_ws, size_t ws_size,
                              hipStream_t stream) {
    const float* x  = (const float*)d_in[0];
    const int*   ei = (const int*)d_in[1];
    const float* W1 = (const float*)d_in[2];
    const float* b1 = (const float*)d_in[3];
    const float* W2 = (const float*)d_in[4];
    const float* b2 = (const float*)d_in[5];
    const float* Wc = (const float*)d_in[6];
    const float* bc = (const float*)d_in[7];

    const int N  = in_sizes[0] / HIDDEN;      // 50000
    const int E  = in_sizes[1] / 2;           // 500000
    const int NC = in_sizes[6] / HIDDEN;      // 100
    const int NB = (N + 127) / 128;           // 391
    const int NSB = (N + 255) / 256;          // scan blocks (196)

    const int* src = ei;
    const int* dst = ei + E;

    // ws layout (KB offsets): cnt@0, rowptr@256, cursor@512, normv@768 (ends ~963.3),
    // bsums@968, boffs@990, epair@1024. NOTE: bsums/boffs MUST sit after normv's end
    // (N*4B = 195.3 KB) — R4's overlap at 900/950 KB clobbered normv.
    char* ws = (char*)d_ws;
    int*   cnt    = (int*)(ws);
    int*   rowptr = (int*)(ws + (256 << 10));
    int*   cursor = (int*)(ws + (512 << 10));
    float* normv  = (float*)(ws + (768 << 10));
    int*   bsums  = (int*)(ws + (968 << 10));
    int*   boffs  = (int*)(ws + (990 << 10));
    int2*  epair  = (int2*)(ws + (1ull << 20));                 // E*8 B = 4 MB
    unsigned short* W1t = (unsigned short*)(ws + (6ull << 20));
    unsigned short* W2t = (unsigned short*)(ws + (6ull << 20) + (512 << 10));
    unsigned short* Wct = (unsigned short*)(ws + (7ull << 20));
    unsigned short* bufA = (unsigned short*)(ws + (16ull << 20));
    unsigned short* bufB = (unsigned short*)(ws + (80ull << 20));
    unsigned short* hbuf = (unsigned short*)(ws + (144ull << 20));

    // CSR + normalization
    hipMemsetAsync(cnt, 0, N * sizeof(int), stream);
    count_kernel<<<(E + 255) / 256, 256, 0, stream>>>(dst, cnt, E);
    norm_kernel<<<(N + 255) / 256, 256, 0, stream>>>(cnt, normv, N);
    bsum_kernel<<<NSB, 256, 0, stream>>>(cnt, bsums, N);
    bscan_kernel<<<1, 256, 0, stream>>>(bsums, boffs, rowptr + N, NSB);
    scan_final_kernel<<<NSB, 256, 0, stream>>>(cnt, boffs, rowptr, cursor, N);
    fill_kernel<<<(E + 255) / 256, 256, 0, stream>>>(src, dst, normv, cursor, epair, E);

    // casts to tiled bf16
    int xchunks = NB * 8192;
    cast_tiled_kernel<<<(xchunks + 255) / 256, 256, 0, stream>>>(x, bufA, N, xchunks);
    cast_tiled_kernel<<<128, 256, 0, stream>>>(W1, W1t, HIDDEN, 4 * 8192);
    cast_tiled_kernel<<<128, 256, 0, stream>>>(W2, W2t, HIDDEN, 4 * 8192);
    cast_tiled_kernel<<<32, 256, 0, stream>>>(Wc, Wct, NC, 8192);

    dim3 gh(NB, 4);
    // layer 1
    gemm_bf16<0><<<gh, 256, 0, stream>>>(bufA, W1t, nullptr, hbuf, N, HIDDEN);
    aggregate_kernel<<<(N + 3) / 4, 256, 0, stream>>>(hbuf, rowptr, epair, normv, b1, bufB, N);
    // layer 2
    gemm_bf16<0><<<gh, 256, 0, stream>>>(bufB, W2t, nullptr, hbuf, N, HIDDEN);
    aggregate_kernel<<<(N + 3) / 4, 256, 0, stream>>>(hbuf, rowptr, epair, normv, b2, bufA, N);
    // head
    dim3 gc(NB, 1);
    gemm_bf16<1><<<gc, 256, 0, stream>>>(bufA, Wct, bc, d_out, N, NC);
}

// Round 6
// 536.579 us; speedup vs baseline: 2.5288x; 1.0437x over previous
//
#include <hip/hip_runtime.h>

#define HIDDEN 512
#define BLK_ELEMS (64 * 128 * 8)   // elements per (128-row x 512-col) tiled block

typedef __attribute__((ext_vector_type(8))) short short8;
typedef __attribute__((ext_vector_type(4))) float f32x4;

__device__ __forceinline__ unsigned short f2bf(float f) {
    unsigned u = __float_as_uint(f);
    unsigned r = (u + 0x7FFFu + ((u >> 16) & 1u)) >> 16;
    return (unsigned short)r;
}
__device__ __forceinline__ float bf2f(unsigned short h) {
    return __uint_as_float(((unsigned)h) << 16);
}

__device__ __forceinline__ void load_lds16(const unsigned short* g, unsigned short* l) {
    __builtin_amdgcn_global_load_lds(
        (const __attribute__((address_space(1))) unsigned int*)(g),
        (__attribute__((address_space(3))) unsigned int*)(l), 16, 0, 0);
}

__device__ __forceinline__ void acc8(uint4 v, float cf, float* a) {
    a[0] = fmaf(cf, bf2f((unsigned short)(v.x & 0xFFFF)), a[0]);
    a[1] = fmaf(cf, bf2f((unsigned short)(v.x >> 16)),    a[1]);
    a[2] = fmaf(cf, bf2f((unsigned short)(v.y & 0xFFFF)), a[2]);
    a[3] = fmaf(cf, bf2f((unsigned short)(v.y >> 16)),    a[3]);
    a[4] = fmaf(cf, bf2f((unsigned short)(v.z & 0xFFFF)), a[4]);
    a[5] = fmaf(cf, bf2f((unsigned short)(v.z >> 16)),    a[5]);
    a[6] = fmaf(cf, bf2f((unsigned short)(v.w & 0xFFFF)), a[6]);
    a[7] = fmaf(cf, bf2f((unsigned short)(v.w >> 16)),    a[7]);
}

// ---------------- CSR build ----------------

__global__ void count_kernel(const int* __restrict__ dst, int* __restrict__ cnt, int E) {
    int e = blockIdx.x * 256 + threadIdx.x;
    if (e < E) atomicAdd(&cnt[dst[e]], 1);
}

// fused: norm[i] = rsqrt(cnt[i]+1) AND per-block partial sums for the scan
__global__ __launch_bounds__(256)
void bsum_norm_kernel(const int* __restrict__ cnt, float* __restrict__ norm,
                      int* __restrict__ bsums, int n) {
    __shared__ int red[256];
    int tid = threadIdx.x;
    int i = blockIdx.x * 256 + tid;
    int v = 0;
    if (i < n) {
        v = cnt[i];
        norm[i] = rsqrtf((float)(v + 1));
    }
    red[tid] = v;
    __syncthreads();
    #pragma unroll
    for (int off = 128; off > 0; off >>= 1) {
        if (tid < off) red[tid] += red[tid + off];
        __syncthreads();
    }
    if (tid == 0) bsums[blockIdx.x] = red[0];
}

// scans nb (<=256) block sums; writes exclusive offsets + total into rowptr[n]
__global__ __launch_bounds__(256)
void bscan_kernel(const int* __restrict__ bsums, int* __restrict__ boffs,
                  int* __restrict__ rowptr_n, int nb) {
    __shared__ int buf[256];
    int tid = threadIdx.x;
    int v = (tid < nb) ? bsums[tid] : 0;
    buf[tid] = v;
    __syncthreads();
    #pragma unroll
    for (int off = 1; off < 256; off <<= 1) {
        int t = (tid >= off) ? buf[tid - off] : 0;
        __syncthreads();
        buf[tid] += t;
        __syncthreads();
    }
    if (tid < nb) boffs[tid] = buf[tid] - v;
    if (tid == 255) rowptr_n[0] = buf[255];
}

__global__ __launch_bounds__(256)
void scan_final_kernel(const int* __restrict__ cnt, const int* __restrict__ boffs,
                       int* __restrict__ rowptr, int* __restrict__ cursor, int n) {
    __shared__ int buf[256];
    int tid = threadIdx.x;
    int i = blockIdx.x * 256 + tid;
    int v = (i < n) ? cnt[i] : 0;
    buf[tid] = v;
    __syncthreads();
    #pragma unroll
    for (int off = 1; off < 256; off <<= 1) {
        int t = (tid >= off) ? buf[tid - off] : 0;
        __syncthreads();
        buf[tid] += t;
        __syncthreads();
    }
    if (i < n) {
        int ex = boffs[blockIdx.x] + buf[tid] - v;
        rowptr[i] = ex;
        cursor[i] = ex;
    }
}

// fill CSR adjacency with fused coef computation; epair = (src, coef-bits)
__global__ void fill_kernel(const int* __restrict__ src, const int* __restrict__ dst,
                            const float* __restrict__ norm, int* __restrict__ cursor,
                            int2* __restrict__ epair, int E) {
    int e = blockIdx.x * 256 + threadIdx.x;
    if (e < E) {
        int s = src[e], d = dst[e];
        float cf = norm[s] * norm[d];
        int p = atomicAdd(&cursor[d], 1);
        epair[p] = make_int2(s, __float_as_int(cf));
    }
}

// ---------------- cast fp32 row-major -> tiled bf16 ----------------
// tiled layout: [row/128][kchunk(64)][row%128][8 bf16]

__device__ __forceinline__ void cast_chunk(const float* __restrict__ src,
                                           unsigned short* __restrict__ dst,
                                           int rows, int o) {
    int blk = o >> 13;
    int rem = o & 8191;
    int g = rem >> 7;
    int m = rem & 127;
    int row = blk * 128 + m;
    short8 v;
    if (row < rows) {
        const float* p = src + (size_t)row * HIDDEN + g * 8;
        float4 f0 = *(const float4*)p;
        float4 f1 = *(const float4*)(p + 4);
        v[0] = (short)f2bf(f0.x); v[1] = (short)f2bf(f0.y);
        v[2] = (short)f2bf(f0.z); v[3] = (short)f2bf(f0.w);
        v[4] = (short)f2bf(f1.x); v[5] = (short)f2bf(f1.y);
        v[6] = (short)f2bf(f1.z); v[7] = (short)f2bf(f1.w);
    } else {
        v = (short8)0;
    }
    *(short8*)(dst + (size_t)o * 8) = v;
}

__global__ __launch_bounds__(256)
void cast_tiled_kernel(const float* __restrict__ src, unsigned short* __restrict__ dst,
                       int rows, int total_chunks) {
    int o = blockIdx.x * 256 + threadIdx.x;
    if (o >= total_chunks) return;
    cast_chunk(src, dst, rows, o);
}

// fused cast of W1 (32768 chunks), W2 (32768), Wc (8192) = 73728 chunks
__global__ __launch_bounds__(256)
void cast_w3_kernel(const float* __restrict__ W1, const float* __restrict__ W2,
                    const float* __restrict__ Wc,
                    unsigned short* __restrict__ W1t, unsigned short* __restrict__ W2t,
                    unsigned short* __restrict__ Wct, int NC) {
    int o = blockIdx.x * 256 + threadIdx.x;
    if (o < 32768) {
        cast_chunk(W1, W1t, HIDDEN, o);
    } else if (o < 65536) {
        cast_chunk(W2, W2t, HIDDEN, o - 32768);
    } else if (o < 73728) {
        cast_chunk(Wc, Wct, NC, o - 65536);
    }
}

// ---------------- bf16 MFMA GEMM ----------------
// C[M,N] = A[M,K] @ W[N,K]^T, A/W in tiled bf16 layout, K=512.
// MODE 0: C bf16 row-major [M][512].  MODE 1: C fp32 [M][NC] + bias, col<NC guard.
// SWIZ 1: 1D grid, XCD-grouped decode — the 4 nb blocks of one mb land on ONE XCD
//         back-to-back (bid%8 = XCD heuristic) so the A tile is fetched into that
//         XCD's L2 once and hit 3x. SWIZ 0: 2D grid (mb, nb).

template<int MODE, int SWIZ>
__global__ __launch_bounds__(256)
void gemm_bf16(const unsigned short* __restrict__ At, const unsigned short* __restrict__ Bt,
               const float* __restrict__ bias, void* __restrict__ Cout,
               int M, int NC, int NB) {
    __shared__ __align__(16) unsigned short As[8 * 128 * 8];  // 16 KB: [g][m][8]
    __shared__ __align__(16) unsigned short Bs[8 * 128 * 8];

    int mb, nb;
    if (SWIZ) {
        int bid = blockIdx.x;
        int p = bid & 7;          // XCD slot
        int s = bid >> 3;         // per-XCD sequence
        nb = s & 3;
        mb = (s >> 2) * 8 + p;
        if (mb >= NB) return;
    } else {
        mb = blockIdx.x;
        nb = blockIdx.y;
    }

    const int tid = threadIdx.x;
    const int wid = tid >> 6;
    const int lane = tid & 63;
    const int wm = wid & 1, wn = wid >> 1;
    const int lm = lane & 15;
    const int lq = lane >> 4;

    const unsigned short* Ab = At + (size_t)mb * BLK_ELEMS;
    const unsigned short* Bb = Bt + (size_t)nb * BLK_ELEMS;

    f32x4 acc[4][4];
    #pragma unroll
    for (int i = 0; i < 4; ++i)
        #pragma unroll
        for (int j = 0; j < 4; ++j) acc[i][j] = (f32x4)0.f;

    for (int kt = 0; kt < 8; ++kt) {
        __syncthreads();
        const unsigned short* ga = Ab + kt * (8 * 1024);
        const unsigned short* gb = Bb + kt * (8 * 1024);
        #pragma unroll
        for (int i = 0; i < 4; ++i) {
            int off = (tid + i * 256) * 8;
            load_lds16(ga + off, As + off);
            load_lds16(gb + off, Bs + off);
        }
        __syncthreads();
        #pragma unroll
        for (int ks = 0; ks < 2; ++ks) {
            int g = ks * 4 + lq;
            int base = g * 1024 + lm * 8;
            short8 af[4], bfr[4];
            #pragma unroll
            for (int mt = 0; mt < 4; ++mt)
                af[mt] = *(const short8*)&As[base + (wm * 64 + mt * 16) * 8];
            #pragma unroll
            for (int nt = 0; nt < 4; ++nt)
                bfr[nt] = *(const short8*)&Bs[base + (wn * 64 + nt * 16) * 8];
            #pragma unroll
            for (int mt = 0; mt < 4; ++mt)
                #pragma unroll
                for (int nt = 0; nt < 4; ++nt)
                    acc[mt][nt] = __builtin_amdgcn_mfma_f32_16x16x32_bf16(
                        af[mt], bfr[nt], acc[mt][nt], 0, 0, 0);
        }
    }

    #pragma unroll
    for (int mt = 0; mt < 4; ++mt) {
        #pragma unroll
        for (int nt = 0; nt < 4; ++nt) {
            int col = nb * 128 + wn * 64 + nt * 16 + lm;
            f32x4 v = acc[mt][nt];
            #pragma unroll
            for (int r = 0; r < 4; ++r) {
                int row = mb * 128 + wm * 64 + mt * 16 + lq * 4 + r;
                if (row < M) {
                    if (MODE == 0) {
                        ((unsigned short*)Cout)[(size_t)row * HIDDEN + col] = f2bf(v[r]);
                    } else {
                        if (col < NC)
                            ((float*)Cout)[(size_t)row * NC + col] = v[r] + bias[col];
                    }
                }
            }
        }
    }
}

// ---------------- aggregation: wave-per-node, 4-deep unrolled gather ----------------
// out[i] = relu( sum_e coef[e]*h[src[e]] + norm[i]^2*h[i] + b ), written tiled-bf16

__global__ __launch_bounds__(256)
void aggregate_kernel(const unsigned short* __restrict__ h, const int* __restrict__ rowptr,
                      const int2* __restrict__ epair, const float* __restrict__ norm,
                      const float* __restrict__ bias, unsigned short* __restrict__ out_t,
                      int N) {
    const int wave = threadIdx.x >> 6;
    const int lane = threadIdx.x & 63;
    const int node = blockIdx.x * 4 + wave;
    if (node >= N) return;
    const uint4* h4 = (const uint4*)h;   // 64 chunks of 16B per row
    const int c = lane;

    float a[8];
    {
        uint4 sv = h4[(size_t)node * 64 + c];
        float nv = norm[node];
        float invd = nv * nv;
        a[0] = a[1] = a[2] = a[3] = a[4] = a[5] = a[6] = a[7] = 0.f;
        acc8(sv, invd, a);
    }

    int beg = rowptr[node], end = rowptr[node + 1];
    int j = beg;
    for (; j + 4 <= end; j += 4) {
        int2 p0 = epair[j + 0];
        int2 p1 = epair[j + 1];
        int2 p2 = epair[j + 2];
        int2 p3 = epair[j + 3];
        uint4 v0 = h4[(size_t)p0.x * 64 + c];
        uint4 v1 = h4[(size_t)p1.x * 64 + c];
        uint4 v2 = h4[(size_t)p2.x * 64 + c];
        uint4 v3 = h4[(size_t)p3.x * 64 + c];
        acc8(v0, __int_as_float(p0.y), a);
        acc8(v1, __int_as_float(p1.y), a);
        acc8(v2, __int_as_float(p2.y), a);
        acc8(v3, __int_as_float(p3.y), a);
    }
    for (; j < end; ++j) {
        int2 p = epair[j];
        uint4 v = h4[(size_t)p.x * 64 + c];
        acc8(v, __int_as_float(p.y), a);
    }

    const float4 b0 = *(const float4*)(bias + c * 8);
    const float4 b1 = *(const float4*)(bias + c * 8 + 4);
    a[0] = fmaxf(a[0] + b0.x, 0.f); a[1] = fmaxf(a[1] + b0.y, 0.f);
    a[2] = fmaxf(a[2] + b0.z, 0.f); a[3] = fmaxf(a[3] + b0.w, 0.f);
    a[4] = fmaxf(a[4] + b1.x, 0.f); a[5] = fmaxf(a[5] + b1.y, 0.f);
    a[6] = fmaxf(a[6] + b1.z, 0.f); a[7] = fmaxf(a[7] + b1.w, 0.f);

    // tiled write: lane owns chunk g=c of this node's row
    size_t off = (size_t)(node >> 7) * BLK_ELEMS + (size_t)c * 1024 + (node & 127) * 8;
    uint4 o;
    o.x = (unsigned)f2bf(a[0]) | ((unsigned)f2bf(a[1]) << 16);
    o.y = (unsigned)f2bf(a[2]) | ((unsigned)f2bf(a[3]) << 16);
    o.z = (unsigned)f2bf(a[4]) | ((unsigned)f2bf(a[5]) << 16);
    o.w = (unsigned)f2bf(a[6]) | ((unsigned)f2bf(a[7]) << 16);
    *(uint4*)(out_t + off) = o;
}

// ---------------- launch ----------------

extern "C" void kernel_launch(void* const* d_in, const int* in_sizes, int n_in,
                              void* d_out, int out_size, void* d_ws, size_t ws_size,
                              hipStream_t stream) {
    const float* x  = (const float*)d_in[0];
    const int*   ei = (const int*)d_in[1];
    const float* W1 = (const float*)d_in[2];
    const float* b1 = (const float*)d_in[3];
    const float* W2 = (const float*)d_in[4];
    const float* b2 = (const float*)d_in[5];
    const float* Wc = (const float*)d_in[6];
    const float* bc = (const float*)d_in[7];

    const int N  = in_sizes[0] / HIDDEN;      // 50000
    const int E  = in_sizes[1] / 2;           // 500000
    const int NC = in_sizes[6] / HIDDEN;      // 100
    const int NB = (N + 127) / 128;           // 391
    const int NSB = (N + 255) / 256;          // scan blocks (196)

    const int* src = ei;
    const int* dst = ei + E;

    // ws layout (KB offsets): cnt@0, rowptr@256, cursor@512, normv@768 (ends ~963.3),
    // bsums@968, boffs@990, epair@1024. bsums/boffs must sit after normv's end.
    char* ws = (char*)d_ws;
    int*   cnt    = (int*)(ws);
    int*   rowptr = (int*)(ws + (256 << 10));
    int*   cursor = (int*)(ws + (512 << 10));
    float* normv  = (float*)(ws + (768 << 10));
    int*   bsums  = (int*)(ws + (968 << 10));
    int*   boffs  = (int*)(ws + (990 << 10));
    int2*  epair  = (int2*)(ws + (1ull << 20));                 // E*8 B = 4 MB
    unsigned short* W1t = (unsigned short*)(ws + (6ull << 20));
    unsigned short* W2t = (unsigned short*)(ws + (6ull << 20) + (512 << 10));
    unsigned short* Wct = (unsigned short*)(ws + (7ull << 20));
    unsigned short* bufA = (unsigned short*)(ws + (16ull << 20));
    unsigned short* bufB = (unsigned short*)(ws + (80ull << 20));
    unsigned short* hbuf = (unsigned short*)(ws + (144ull << 20));

    // CSR + normalization
    hipMemsetAsync(cnt, 0, N * sizeof(int), stream);
    count_kernel<<<(E + 255) / 256, 256, 0, stream>>>(dst, cnt, E);
    bsum_norm_kernel<<<NSB, 256, 0, stream>>>(cnt, normv, bsums, N);
    bscan_kernel<<<1, 256, 0, stream>>>(bsums, boffs, rowptr + N, NSB);
    scan_final_kernel<<<NSB, 256, 0, stream>>>(cnt, boffs, rowptr, cursor, N);
    fill_kernel<<<(E + 255) / 256, 256, 0, stream>>>(src, dst, normv, cursor, epair, E);

    // casts to tiled bf16
    int xchunks = NB * 8192;
    cast_tiled_kernel<<<(xchunks + 255) / 256, 256, 0, stream>>>(x, bufA, N, xchunks);
    cast_w3_kernel<<<288, 256, 0, stream>>>(W1, W2, Wc, W1t, W2t, Wct, NC);

    // hidden gemms: 1D XCD-grouped grid: 8 XCD slots x 4 nb x ceil(NB/8) mb-groups
    const int gswz = 8 * 4 * ((NB + 7) / 8);
    // layer 1
    gemm_bf16<0, 1><<<gswz, 256, 0, stream>>>(bufA, W1t, nullptr, hbuf, N, HIDDEN, NB);
    aggregate_kernel<<<(N + 3) / 4, 256, 0, stream>>>(hbuf, rowptr, epair, normv, b1, bufB, N);
    // layer 2
    gemm_bf16<0, 1><<<gswz, 256, 0, stream>>>(bufB, W2t, nullptr, hbuf, N, HIDDEN, NB);
    aggregate_kernel<<<(N + 3) / 4, 256, 0, stream>>>(hbuf, rowptr, epair, normv, b2, bufA, N);
    // head
    dim3 gc(NB, 1);
    gemm_bf16<1, 0><<<gc, 256, 0, stream>>>(bufA, Wct, bc, d_out, N, NC, NB);
}

// Round 7
// 514.116 us; speedup vs baseline: 2.6393x; 1.0437x over previous
//
#include <hip/hip_runtime.h>

#define HIDDEN 512
#define BLK_ELEMS (64 * 128 * 8)   // elements per (128-row x 512-col) tiled block

typedef __attribute__((ext_vector_type(8))) short short8;
typedef __attribute__((ext_vector_type(4))) float f32x4;

__device__ __forceinline__ unsigned short f2bf(float f) {
    unsigned u = __float_as_uint(f);
    unsigned r = (u + 0x7FFFu + ((u >> 16) & 1u)) >> 16;
    return (unsigned short)r;
}
__device__ __forceinline__ float bf2f(unsigned short h) {
    return __uint_as_float(((unsigned)h) << 16);
}

__device__ __forceinline__ void load_lds16(const unsigned short* g, unsigned short* l) {
    __builtin_amdgcn_global_load_lds(
        (const __attribute__((address_space(1))) unsigned int*)(g),
        (__attribute__((address_space(3))) unsigned int*)(l), 16, 0, 0);
}

__device__ __forceinline__ void acc8(uint4 v, float cf, float* a) {
    a[0] = fmaf(cf, bf2f((unsigned short)(v.x & 0xFFFF)), a[0]);
    a[1] = fmaf(cf, bf2f((unsigned short)(v.x >> 16)),    a[1]);
    a[2] = fmaf(cf, bf2f((unsigned short)(v.y & 0xFFFF)), a[2]);
    a[3] = fmaf(cf, bf2f((unsigned short)(v.y >> 16)),    a[3]);
    a[4] = fmaf(cf, bf2f((unsigned short)(v.z & 0xFFFF)), a[4]);
    a[5] = fmaf(cf, bf2f((unsigned short)(v.z >> 16)),    a[5]);
    a[6] = fmaf(cf, bf2f((unsigned short)(v.w & 0xFFFF)), a[6]);
    a[7] = fmaf(cf, bf2f((unsigned short)(v.w >> 16)),    a[7]);
}

// ---------------- cast fp32 row-major -> tiled bf16 ----------------
// tiled layout: [row/128][kchunk(64)][row%128][8 bf16]

__device__ __forceinline__ void cast_chunk(const float* __restrict__ src,
                                           unsigned short* __restrict__ dst,
                                           int rows, int o) {
    int blk = o >> 13;
    int rem = o & 8191;
    int g = rem >> 7;
    int m = rem & 127;
    int row = blk * 128 + m;
    short8 v;
    if (row < rows) {
        const float* p = src + (size_t)row * HIDDEN + g * 8;
        float4 f0 = *(const float4*)p;
        float4 f1 = *(const float4*)(p + 4);
        v[0] = (short)f2bf(f0.x); v[1] = (short)f2bf(f0.y);
        v[2] = (short)f2bf(f0.z); v[3] = (short)f2bf(f0.w);
        v[4] = (short)f2bf(f1.x); v[5] = (short)f2bf(f1.y);
        v[6] = (short)f2bf(f1.z); v[7] = (short)f2bf(f1.w);
    } else {
        v = (short8)0;
    }
    *(short8*)(dst + (size_t)o * 8) = v;
}

// ---------------- fused: edge-count | cast x ----------------

__global__ __launch_bounds__(256)
void fused_count_castx(const int* __restrict__ dstv, int* __restrict__ cnt, int E, int countB,
                       const float* __restrict__ x, unsigned short* __restrict__ bufA,
                       int rows, int xchunks) {
    int b = blockIdx.x;
    if (b < countB) {
        int e = b * 256 + threadIdx.x;
        if (e < E) atomicAdd(&cnt[dstv[e]], 1);
    } else {
        int o = (b - countB) * 256 + threadIdx.x;
        if (o < xchunks) cast_chunk(x, bufA, rows, o);
    }
}

// ---------------- fused: per-block sums + norm | cast W1/W2/Wc ----------------

__global__ __launch_bounds__(256)
void fused_bsum_castw(const int* __restrict__ cnt, float* __restrict__ norm,
                      int* __restrict__ bsums, int n, int NSB,
                      const float* __restrict__ W1, const float* __restrict__ W2,
                      const float* __restrict__ Wc,
                      unsigned short* __restrict__ W1t, unsigned short* __restrict__ W2t,
                      unsigned short* __restrict__ Wct, int NC) {
    __shared__ int red[256];
    int tid = threadIdx.x;
    if ((int)blockIdx.x < NSB) {
        int i = blockIdx.x * 256 + tid;
        int v = 0;
        if (i < n) {
            v = cnt[i];
            norm[i] = rsqrtf((float)(v + 1));
        }
        red[tid] = v;
        __syncthreads();
        #pragma unroll
        for (int off = 128; off > 0; off >>= 1) {
            if (tid < off) red[tid] += red[tid + off];
            __syncthreads();
        }
        if (tid == 0) bsums[blockIdx.x] = red[0];
    } else {
        int o = ((int)blockIdx.x - NSB) * 256 + tid;
        if (o < 32768) {
            cast_chunk(W1, W1t, HIDDEN, o);
        } else if (o < 65536) {
            cast_chunk(W2, W2t, HIDDEN, o - 32768);
        } else if (o < 73728) {
            cast_chunk(Wc, Wct, NC, o - 65536);
        }
    }
}

// scans nb (<=256) block sums; writes exclusive offsets + total into rowptr[n]
__global__ __launch_bounds__(256)
void bscan_kernel(const int* __restrict__ bsums, int* __restrict__ boffs,
                  int* __restrict__ rowptr_n, int nb) {
    __shared__ int buf[256];
    int tid = threadIdx.x;
    int v = (tid < nb) ? bsums[tid] : 0;
    buf[tid] = v;
    __syncthreads();
    #pragma unroll
    for (int off = 1; off < 256; off <<= 1) {
        int t = (tid >= off) ? buf[tid - off] : 0;
        __syncthreads();
        buf[tid] += t;
        __syncthreads();
    }
    if (tid < nb) boffs[tid] = buf[tid] - v;
    if (tid == 255) rowptr_n[0] = buf[255];
}

__global__ __launch_bounds__(256)
void scan_final_kernel(const int* __restrict__ cnt, const int* __restrict__ boffs,
                       int* __restrict__ rowptr, int* __restrict__ cursor, int n) {
    __shared__ int buf[256];
    int tid = threadIdx.x;
    int i = blockIdx.x * 256 + tid;
    int v = (i < n) ? cnt[i] : 0;
    buf[tid] = v;
    __syncthreads();
    #pragma unroll
    for (int off = 1; off < 256; off <<= 1) {
        int t = (tid >= off) ? buf[tid - off] : 0;
        __syncthreads();
        buf[tid] += t;
        __syncthreads();
    }
    if (i < n) {
        int ex = boffs[blockIdx.x] + buf[tid] - v;
        rowptr[i] = ex;
        cursor[i] = ex;
    }
}

// ---------------- bf16 MFMA GEMM body ----------------
// C[M,N] = A[M,K] @ W[N,K]^T, A/W tiled bf16, K=512.
// MODE 0: C bf16 row-major [M][512].  MODE 1: C fp32 [M][NC] + bias, col<NC guard.

template<int MODE>
__device__ __forceinline__ void gemm_body(const unsigned short* __restrict__ At,
                                          const unsigned short* __restrict__ Bt,
                                          const float* __restrict__ bias,
                                          void* __restrict__ Cout,
                                          int M, int NC, int mb, int nb) {
    __shared__ __align__(16) unsigned short As[8 * 128 * 8];  // 16 KB: [g][m][8]
    __shared__ __align__(16) unsigned short Bs[8 * 128 * 8];

    const int tid = threadIdx.x;
    const int wid = tid >> 6;
    const int lane = tid & 63;
    const int wm = wid & 1, wn = wid >> 1;
    const int lm = lane & 15;
    const int lq = lane >> 4;

    const unsigned short* Ab = At + (size_t)mb * BLK_ELEMS;
    const unsigned short* Bb = Bt + (size_t)nb * BLK_ELEMS;

    f32x4 acc[4][4];
    #pragma unroll
    for (int i = 0; i < 4; ++i)
        #pragma unroll
        for (int j = 0; j < 4; ++j) acc[i][j] = (f32x4)0.f;

    for (int kt = 0; kt < 8; ++kt) {
        __syncthreads();
        const unsigned short* ga = Ab + kt * (8 * 1024);
        const unsigned short* gb = Bb + kt * (8 * 1024);
        #pragma unroll
        for (int i = 0; i < 4; ++i) {
            int off = (tid + i * 256) * 8;
            load_lds16(ga + off, As + off);
            load_lds16(gb + off, Bs + off);
        }
        __syncthreads();
        #pragma unroll
        for (int ks = 0; ks < 2; ++ks) {
            int g = ks * 4 + lq;
            int base = g * 1024 + lm * 8;
            short8 af[4], bfr[4];
            #pragma unroll
            for (int mt = 0; mt < 4; ++mt)
                af[mt] = *(const short8*)&As[base + (wm * 64 + mt * 16) * 8];
            #pragma unroll
            for (int nt = 0; nt < 4; ++nt)
                bfr[nt] = *(const short8*)&Bs[base + (wn * 64 + nt * 16) * 8];
            #pragma unroll
            for (int mt = 0; mt < 4; ++mt)
                #pragma unroll
                for (int nt = 0; nt < 4; ++nt)
                    acc[mt][nt] = __builtin_amdgcn_mfma_f32_16x16x32_bf16(
                        af[mt], bfr[nt], acc[mt][nt], 0, 0, 0);
        }
    }

    #pragma unroll
    for (int mt = 0; mt < 4; ++mt) {
        #pragma unroll
        for (int nt = 0; nt < 4; ++nt) {
            int col = nb * 128 + wn * 64 + nt * 16 + lm;
            f32x4 v = acc[mt][nt];
            #pragma unroll
            for (int r = 0; r < 4; ++r) {
                int row = mb * 128 + wm * 64 + mt * 16 + lq * 4 + r;
                if (row < M) {
                    if (MODE == 0) {
                        ((unsigned short*)Cout)[(size_t)row * HIDDEN + col] = f2bf(v[r]);
                    } else {
                        if (col < NC)
                            ((float*)Cout)[(size_t)row * NC + col] = v[r] + bias[col];
                    }
                }
            }
        }
    }
}

// XCD-grouped swizzle: 4 nb blocks of one mb land on one XCD back-to-back
__device__ __forceinline__ bool swz_decode(int bid, int NB, int& mb, int& nb) {
    int p = bid & 7;
    int s = bid >> 3;
    nb = s & 3;
    mb = (s >> 2) * 8 + p;
    return mb < NB;
}

template<int MODE>
__global__ __launch_bounds__(256)
void gemm_swz(const unsigned short* __restrict__ At, const unsigned short* __restrict__ Bt,
              const float* __restrict__ bias, void* __restrict__ Cout,
              int M, int NC, int NB) {
    int mb, nb;
    if (!swz_decode(blockIdx.x, NB, mb, nb)) return;
    gemm_body<MODE>(At, Bt, bias, Cout, M, NC, mb, nb);
}

template<int MODE>
__global__ __launch_bounds__(256)
void gemm_plain(const unsigned short* __restrict__ At, const unsigned short* __restrict__ Bt,
                const float* __restrict__ bias, void* __restrict__ Cout,
                int M, int NC) {
    gemm_body<MODE>(At, Bt, bias, Cout, M, NC, blockIdx.x, blockIdx.y);
}

// ---------------- fused: CSR fill | gemm layer-1 ----------------

__global__ __launch_bounds__(256)
void fused_fill_gemm1(const int* __restrict__ src, const int* __restrict__ dstv,
                      const float* __restrict__ norm, int* __restrict__ cursor,
                      int2* __restrict__ epair, int E, int fillB,
                      const unsigned short* __restrict__ At, const unsigned short* __restrict__ Bt,
                      void* __restrict__ Cout, int M, int NB) {
    int b = blockIdx.x;
    if (b < fillB) {
        int e = b * 256 + threadIdx.x;
        if (e < E) {
            int s = src[e], d = dstv[e];
            float cf = norm[s] * norm[d];
            int p = atomicAdd(&cursor[d], 1);
            epair[p] = make_int2(s, __float_as_int(cf));
        }
    } else {
        int mb, nb;
        if (swz_decode(b - fillB, NB, mb, nb))
            gemm_body<0>(At, Bt, nullptr, Cout, M, HIDDEN, mb, nb);
    }
}

// ---------------- aggregation: wave-per-node, 8-deep unrolled gather ----------------
// out[i] = relu( sum_e coef[e]*h[src[e]] + norm[i]^2*h[i] + b ), written tiled-bf16

__global__ __launch_bounds__(256)
void aggregate_kernel(const unsigned short* __restrict__ h, const int* __restrict__ rowptr,
                      const int2* __restrict__ epair, const float* __restrict__ norm,
                      const float* __restrict__ bias, unsigned short* __restrict__ out_t,
                      int N) {
    const int wave = threadIdx.x >> 6;
    const int lane = threadIdx.x & 63;
    const int node = blockIdx.x * 4 + wave;
    if (node >= N) return;
    const uint4* h4 = (const uint4*)h;   // 64 chunks of 16B per row
    const int c = lane;

    float a[8];
    {
        uint4 sv = h4[(size_t)node * 64 + c];
        float nv = norm[node];
        float invd = nv * nv;
        a[0] = a[1] = a[2] = a[3] = a[4] = a[5] = a[6] = a[7] = 0.f;
        acc8(sv, invd, a);
    }

    int beg = rowptr[node], end = rowptr[node + 1];
    int j = beg;
    // alignment prologue: make j even so int4 (2-edge) loads are 16B aligned
    if ((j & 1) && j < end) {
        int2 p = epair[j];
        uint4 v = h4[(size_t)p.x * 64 + c];
        acc8(v, __int_as_float(p.y), a);
        ++j;
    }
    for (; j + 8 <= end; j += 8) {
        int4 q0 = *(const int4*)(epair + j);      // {src0,coef0,src1,coef1}
        int4 q1 = *(const int4*)(epair + j + 2);
        int4 q2 = *(const int4*)(epair + j + 4);
        int4 q3 = *(const int4*)(epair + j + 6);
        uint4 v0 = h4[(size_t)q0.x * 64 + c];
        uint4 v1 = h4[(size_t)q0.z * 64 + c];
        uint4 v2 = h4[(size_t)q1.x * 64 + c];
        uint4 v3 = h4[(size_t)q1.z * 64 + c];
        uint4 v4 = h4[(size_t)q2.x * 64 + c];
        uint4 v5 = h4[(size_t)q2.z * 64 + c];
        uint4 v6 = h4[(size_t)q3.x * 64 + c];
        uint4 v7 = h4[(size_t)q3.z * 64 + c];
        acc8(v0, __int_as_float(q0.y), a);
        acc8(v1, __int_as_float(q0.w), a);
        acc8(v2, __int_as_float(q1.y), a);
        acc8(v3, __int_as_float(q1.w), a);
        acc8(v4, __int_as_float(q2.y), a);
        acc8(v5, __int_as_float(q2.w), a);
        acc8(v6, __int_as_float(q3.y), a);
        acc8(v7, __int_as_float(q3.w), a);
    }
    for (; j < end; ++j) {
        int2 p = epair[j];
        uint4 v = h4[(size_t)p.x * 64 + c];
        acc8(v, __int_as_float(p.y), a);
    }

    const float4 b0 = *(const float4*)(bias + c * 8);
    const float4 b1 = *(const float4*)(bias + c * 8 + 4);
    a[0] = fmaxf(a[0] + b0.x, 0.f); a[1] = fmaxf(a[1] + b0.y, 0.f);
    a[2] = fmaxf(a[2] + b0.z, 0.f); a[3] = fmaxf(a[3] + b0.w, 0.f);
    a[4] = fmaxf(a[4] + b1.x, 0.f); a[5] = fmaxf(a[5] + b1.y, 0.f);
    a[6] = fmaxf(a[6] + b1.z, 0.f); a[7] = fmaxf(a[7] + b1.w, 0.f);

    // tiled write: lane owns chunk g=c of this node's row
    size_t off = (size_t)(node >> 7) * BLK_ELEMS + (size_t)c * 1024 + (node & 127) * 8;
    uint4 o;
    o.x = (unsigned)f2bf(a[0]) | ((unsigned)f2bf(a[1]) << 16);
    o.y = (unsigned)f2bf(a[2]) | ((unsigned)f2bf(a[3]) << 16);
    o.z = (unsigned)f2bf(a[4]) | ((unsigned)f2bf(a[5]) << 16);
    o.w = (unsigned)f2bf(a[6]) | ((unsigned)f2bf(a[7]) << 16);
    *(uint4*)(out_t + off) = o;
}

// ---------------- launch ----------------

extern "C" void kernel_launch(void* const* d_in, const int* in_sizes, int n_in,
                              void* d_out, int out_size, void* d_ws, size_t ws_size,
                              hipStream_t stream) {
    const float* x  = (const float*)d_in[0];
    const int*   ei = (const int*)d_in[1];
    const float* W1 = (const float*)d_in[2];
    const float* b1 = (const float*)d_in[3];
    const float* W2 = (const float*)d_in[4];
    const float* b2 = (const float*)d_in[5];
    const float* Wc = (const float*)d_in[6];
    const float* bc = (const float*)d_in[7];

    const int N  = in_sizes[0] / HIDDEN;      // 50000
    const int E  = in_sizes[1] / 2;           // 500000
    const int NC = in_sizes[6] / HIDDEN;      // 100
    const int NB = (N + 127) / 128;           // 391
    const int NSB = (N + 255) / 256;          // 196

    const int* src = ei;
    const int* dst = ei + E;

    // ws layout (KB offsets): cnt@0, rowptr@256, cursor@512, normv@768 (ends ~963.3),
    // bsums@968, boffs@990, epair@1024. bsums/boffs must sit after normv's end.
    char* ws = (char*)d_ws;
    int*   cnt    = (int*)(ws);
    int*   rowptr = (int*)(ws + (256 << 10));
    int*   cursor = (int*)(ws + (512 << 10));
    float* normv  = (float*)(ws + (768 << 10));
    int*   bsums  = (int*)(ws + (968 << 10));
    int*   boffs  = (int*)(ws + (990 << 10));
    int2*  epair  = (int2*)(ws + (1ull << 20));                 // E*8 B = 4 MB
    unsigned short* W1t = (unsigned short*)(ws + (6ull << 20));
    unsigned short* W2t = (unsigned short*)(ws + (6ull << 20) + (512 << 10));
    unsigned short* Wct = (unsigned short*)(ws + (7ull << 20));
    unsigned short* bufA = (unsigned short*)(ws + (16ull << 20));
    unsigned short* bufB = (unsigned short*)(ws + (80ull << 20));
    unsigned short* hbuf = (unsigned short*)(ws + (144ull << 20));

    const int countB = (E + 255) / 256;                 // 1954
    const int xchunks = NB * 8192;
    const int castxB = (xchunks + 255) / 256;           // 12512
    const int gemmB = 8 * 4 * ((NB + 7) / 8);           // 1568

    hipMemsetAsync(cnt, 0, N * sizeof(int), stream);
    // [edge count | cast x]
    fused_count_castx<<<countB + castxB, 256, 0, stream>>>(dst, cnt, E, countB,
                                                           x, bufA, N, xchunks);
    // [block sums + norm | cast W1/W2/Wc]
    fused_bsum_castw<<<NSB + 288, 256, 0, stream>>>(cnt, normv, bsums, N, NSB,
                                                    W1, W2, Wc, W1t, W2t, Wct, NC);
    bscan_kernel<<<1, 256, 0, stream>>>(bsums, boffs, rowptr + N, NSB);
    scan_final_kernel<<<NSB, 256, 0, stream>>>(cnt, boffs, rowptr, cursor, N);
    // [CSR fill | gemm layer-1]  (fill needs scan_final; gemm1 needs only the casts)
    fused_fill_gemm1<<<countB + gemmB, 256, 0, stream>>>(src, dst, normv, cursor, epair,
                                                         E, countB,
                                                         bufA, W1t, hbuf, N, NB);
    aggregate_kernel<<<(N + 3) / 4, 256, 0, stream>>>(hbuf, rowptr, epair, normv, b1, bufB, N);
    gemm_swz<0><<<gemmB, 256, 0, stream>>>(bufB, W2t, nullptr, hbuf, N, HIDDEN, NB);
    aggregate_kernel<<<(N + 3) / 4, 256, 0, stream>>>(hbuf, rowptr, epair, normv, b2, bufA, N);
    gemm_plain<1><<<dim3(NB, 1), 256, 0, stream>>>(bufA, Wct, bc, d_out, N, NC);
}